// Round 11
// baseline (194.986 us; speedup 1.0000x reference)
//
#include <hip/hip_runtime.h>

typedef _Float16 half2_t __attribute__((ext_vector_type(2)));
typedef float float4_t __attribute__((ext_vector_type(4)));
typedef unsigned long long u64;

#define U_PAR 0.45f
#define A_STD 0.006667f
#define A_STF 0.05f
#define DT_S  0.01f

#define T_STEPS 64
#define BATCH   16
#define NIN     64
#define NH      256
#define NOUT    16

// d_out layout (floats): h_all (65,16,256) | y (64,16,16) | sx_all (65,16,256,256) | su_all
#define H_OFF  0
#define H_SZ   ((T_STEPS + 1) * BATCH * NH)            // 266240
#define Y_OFF  H_SZ
#define Y_SZ   (T_STEPS * BATCH * NOUT)                // 16384
#define SX_OFF (Y_OFF + Y_SZ)                          // 282624
#define PLANE  ((T_STEPS + 1) * BATCH * NH)            // 266240 compact elems per array
#define SX_SZ  ((size_t)PLANE * NH)
#define SU_OFF ((size_t)SX_OFF + SX_SZ)

#define GROUP    32                                     // rows per consumer iteration
#define N_ROWS   (2 * PLANE)                            // 532480 broadcast rows
#define N_GROUPS (N_ROWS / GROUP)                       // 16640
#define TAG_BASE 0x5EED0000u                            // high word of packed u64

static __device__ __forceinline__ float fdot2f(half2_t a, half2_t b, float c) {
#if __has_builtin(__builtin_amdgcn_fdot2)
  return __builtin_amdgcn_fdot2(a, b, c, false);
#else
  return c + (float)a.x * (float)b.x + (float)a.y * (float)b.y;
#endif
}

// LDS-only barrier: waits ds ops, NOT outstanding global stores (vmcnt).
// asm memory clobbers fence the compiler on both sides of s_barrier.
static __device__ __forceinline__ void bar_lds() {
  asm volatile("s_waitcnt lgkmcnt(0)" ::: "memory");
  __builtin_amdgcn_s_barrier();
  asm volatile("" ::: "memory");
}

// ======================= Fused cooperative kernel ===========================
// A/B vs round 7 (136.8 us, best): the ONLY change is the consumer store
// instruction — nontemporal -> PLAIN float4 store. Rationale: the harness
// fill kernel sustains 6.6 TB/s on this exact buffer with plain stores
// (through L2/L3 streaming); NT bypasses the caches and the fused kernel
// only reaches ~4 TB/s. Full-line coalesced writes -> no RFO expected.
// blocks 0..15: producer (batch b = blockIdx.x), 256 threads, thread j owns
//   column j, W_rec column in 128 half2 regs. Each compact state element is
//   published as ONE relaxed agent-scope u64 store: high word = generation
//   tag TAG_BASE|((t+1)<<4|b), low word = f32 bits (single-copy atomic ->
//   no flag/data race).
// blocks 16.. : consumers, double-buffered: lanes 0-31 of wave 0 poll their
//   own u64 (tag match => value in hand) for group g+stride into sval[buf^1]
//   while all 4 waves issue group g's 32KB of plain float4 stores.
__global__ __launch_bounds__(256, 2) void rnn_fused(
    const float* __restrict__ x, const float* __restrict__ Win,
    const float* __restrict__ Wrec, const float* __restrict__ Wbias,
    const float* __restrict__ Wout, const float* __restrict__ Woutb,
    float* __restrict__ out, u64* __restrict__ wsx64, u64* __restrict__ wsu64)
{
  if (blockIdx.x < BATCH) {
    // ----------------------------- producer ---------------------------------
    __builtin_amdgcn_s_setprio(1);
    const int b = blockIdx.x;
    const int j = threadIdx.x;           // 0..255
    const int wv = j >> 6, lane = j & 63;

    __shared__ __align__(16) _Float16 g_h[NH];
    __shared__ __align__(16) _Float16 x_h[NIN];
    __shared__ float hs[NH];
    __shared__ float red_s[4];
    __shared__ float ypart[4][NOUT];

    half2_t w2[128];
#pragma unroll
    for (int k = 0; k < 128; ++k) {
      float a0 = Wrec[(2 * k) * NH + j];
      float a1 = Wrec[(2 * k + 1) * NH + j];
      half2_t v; v.x = (_Float16)a0; v.y = (_Float16)a1;
      w2[k] = v;
    }
    half2_t win2[32];
#pragma unroll
    for (int k = 0; k < 32; ++k) {
      float a0 = Win[(2 * k) * NH + j];
      float a1 = Win[(2 * k + 1) * NH + j];
      half2_t v; v.x = (_Float16)a0; v.y = (_Float16)a1;
      win2[k] = v;
    }
    const int chunk = j >> 4, o = j & 15;
    float wseg[16];
#pragma unroll
    for (int m = 0; m < 16; ++m) wseg[m] = Wout[(chunk * 16 + m) * NOUT + o];
    const float bias = Wbias[j];

    float h = 0.f, sx = 1.f, su = U_PAR;   // su0 = U_std + 1 = 0.45
    out[H_OFF + b * NH + j] = 0.f;         // h_all[0]

    for (int t = 0; t < T_STEPS; ++t) {
      if (j < NIN) x_h[j] = (_Float16)x[(size_t)(t * BATCH + b) * NIN + j];
      float s = h;
#pragma unroll
      for (int m = 1; m < 64; m <<= 1) s += __shfl_xor(s, m, 64);
      if (lane == 0) red_s[wv] = s;
      __syncthreads();                                   // B1

      float S = red_s[0] + red_s[1] + red_s[2] + red_s[3];
      float sxn = sx + A_STD * (1.f - sx) - DT_S * su * sx * h;
      float sun = su + A_STF * (U_PAR - su) + DT_S * (U_PAR * (1.f - su) * S);
      sxn = fminf(fmaxf(sxn, 0.f), 1.f);
      sun = fminf(fmaxf(sun, 0.f), 1.f);
      g_h[j] = (_Float16)(h * sxn * sun);
      const int row = (t + 1) * BATCH + b;               // compact state row
      {
        u64 tg = (u64)(TAG_BASE | (unsigned)row) << 32;
        u64 px = tg | (u64)__float_as_uint(sxn);
        u64 pu = tg | (u64)__float_as_uint(sun);
        __hip_atomic_store(&wsx64[(size_t)row * NH + j], px,
                           __ATOMIC_RELAXED, __HIP_MEMORY_SCOPE_AGENT);
        __hip_atomic_store(&wsu64[(size_t)row * NH + j], pu,
                           __ATOMIC_RELAXED, __HIP_MEMORY_SCOPE_AGENT);
      }
      sx = sxn; su = sun;

      float xw = 0.f;
      {
        const half2_t* x2 = (const half2_t*)x_h;
        float xa0 = 0.f, xa1 = 0.f;
#pragma unroll
        for (int k = 0; k < 32; k += 2) {
          xa0 = fdot2f(win2[k], x2[k], xa0);
          xa1 = fdot2f(win2[k + 1], x2[k + 1], xa1);
        }
        xw = xa0 + xa1;
      }
      __syncthreads();                                   // B2: g_h ready

      float a0 = 0.f, a1 = 0.f, a2 = 0.f, a3 = 0.f;
      {
        const half2_t* g2 = (const half2_t*)g_h;
#pragma unroll
        for (int k = 0; k < 128; k += 4) {
          a0 = fdot2f(w2[k],     g2[k],     a0);
          a1 = fdot2f(w2[k + 1], g2[k + 1], a1);
          a2 = fdot2f(w2[k + 2], g2[k + 2], a2);
          a3 = fdot2f(w2[k + 3], g2[k + 3], a3);
        }
      }
      float rec = (a0 + a1) + (a2 + a3);
      float hn = fmaxf(0.9f * h + 0.1f * (rec + bias) + xw, 0.f);
      out[H_OFF + (size_t)row * NH + j] = hn;
      hs[j] = hn;
      h = hn;
      __syncthreads();                                   // B3: hs ready

      float yp = 0.f;
      {
        float y0 = 0.f, y1 = 0.f;
#pragma unroll
        for (int m = 0; m < 16; m += 2) {
          y0 = fmaf(hs[chunk * 16 + m],     wseg[m],     y0);
          y1 = fmaf(hs[chunk * 16 + m + 1], wseg[m + 1], y1);
        }
        yp = y0 + y1;
      }
      yp += __shfl_xor(yp, 16, 64);
      yp += __shfl_xor(yp, 32, 64);
      if (lane < NOUT) ypart[wv][lane] = yp;
      __syncthreads();                                   // B4: ypart ready

      if (j < NOUT) {
        float v = ypart[0][j] + ypart[1][j] + ypart[2][j] + ypart[3][j] + Woutb[j];
        out[Y_OFF + (size_t)(t * BATCH + b) * NOUT + j] = 1.f / (1.f + expf(-v));
      }
    }
    __builtin_amdgcn_s_setprio(0);
  } else {
    // --------------------- consumers (double-buffered) ----------------------
    const int nCons = (int)gridDim.x - BATCH;
    const int cb    = (int)blockIdx.x - BATCH;
    const int tid   = threadIdx.x;
    __shared__ float sval[2][GROUP];

    // stage group g's 32 values into sval[buf]; tid<32 only. Each lane polls
    // its OWN tagged u64 — tag match means the payload IS the data.
    auto stageFn = [&](int g, int buf) {
      int r0    = g * GROUP;
      int t     = r0 >> 13;          // 8192 rows per t-slice
      int rem   = r0 & 8191;
      int which = rem >> 12;
      int b     = (rem >> 8) & 15;
      int i0    = rem & 255;
      if (t == 0) {
        sval[buf][tid] = which ? U_PAR : 1.0f;
        return;
      }
      int row = (t << 4) | b;
      unsigned exp = TAG_BASE | (unsigned)row;
      const u64* src = (which ? wsu64 : wsx64) + (size_t)row * NH + i0 + tid;
      u64 v = __hip_atomic_load(src, __ATOMIC_RELAXED, __HIP_MEMORY_SCOPE_AGENT);
      while ((unsigned)(v >> 32) != exp) {
        __builtin_amdgcn_s_sleep(32);
        v = __hip_atomic_load(src, __ATOMIC_RELAXED, __HIP_MEMORY_SCOPE_AGENT);
      }
      sval[buf][tid] = __uint_as_float((unsigned)(v & 0xFFFFFFFFu));
    };

    if (cb < N_GROUPS && tid < GROUP) stageFn(cb, 0);
    int k = 0;
    for (int g = cb; g < N_GROUPS; g += nCons, ++k) {
      int buf = k & 1;
      bar_lds();                     // sval[buf] ready; WAR from iter k-1 done
      int gn = g + nCons;
      if (gn < N_GROUPS && tid < GROUP) stageFn(gn, buf ^ 1);

      int r0    = g * GROUP;
      int t     = r0 >> 13;
      int rem   = r0 & 8191;
      int which = rem >> 12;
      int b     = (rem >> 8) & 15;
      int i0    = rem & 255;
      size_t rowbase = (size_t)(((t << 4) | b) * NH + i0);
      float* dstBase = out + (which ? SU_OFF : (size_t)SX_OFF) + rowbase * NH;
#pragma unroll
      for (int p = 0; p < 8; ++p) {  // 32 rows * 64 float4 = 32 KB
        int id = p * 256 + tid;
        int rr = id >> 6, c = id & 63;
        float v = sval[buf][rr];
        float4_t f4 = {v, v, v, v};
        *((float4_t*)(dstBase + (size_t)rr * NH) + c) = f4;   // PLAIN store (A/B)
      }
    }
  }
}

// ===================== Fallback: proven 3-kernel path =======================
__global__ __launch_bounds__(512) void rnn_phase1(
    const float* __restrict__ x, const float* __restrict__ Win,
    const float* __restrict__ Wrec, const float* __restrict__ Wbias,
    float* __restrict__ out)
{
  const int b   = blockIdx.x;
  const int tid = threadIdx.x;
  const int j   = tid & 255;
  const int q   = tid >> 8;

  __shared__ __align__(16) _Float16 g_h[NH];
  __shared__ __align__(16) _Float16 x_h[NIN];
  __shared__ float p_s[NH];
  __shared__ float xw_s[NH];
  __shared__ float red_s[8];

  half2_t w2[64];
#pragma unroll
  for (int k = 0; k < 64; ++k) {
    float a0 = Wrec[(q * 128 + 2 * k) * NH + j];
    float a1 = Wrec[(q * 128 + 2 * k + 1) * NH + j];
    half2_t v; v.x = (_Float16)a0; v.y = (_Float16)a1;
    w2[k] = v;
  }
  half2_t win2[32];
  if (q == 1) {
#pragma unroll
    for (int k = 0; k < 32; ++k) {
      float a0 = Win[(2 * k) * NH + j];
      float a1 = Win[(2 * k + 1) * NH + j];
      half2_t v; v.x = (_Float16)a0; v.y = (_Float16)a1;
      win2[k] = v;
    }
  }

  float h = 0.f, sx = 1.f, su = U_PAR;
  float bias = 0.f;
  if (q == 0) bias = Wbias[j];

  if (q == 0) {
    out[H_OFF + b * NH + j] = 0.f;
    size_t row0 = (size_t)b * NH + j;
    out[SX_OFF + row0 * NH] = 1.f;
    out[SU_OFF + row0 * NH] = U_PAR;
  }

  for (int t = 0; t < T_STEPS; ++t) {
    if (q == 0) {
      float s = h;
#pragma unroll
      for (int m = 1; m < 64; m <<= 1) s += __shfl_xor(s, m, 64);
      if ((tid & 63) == 0) red_s[tid >> 6] = s;
    } else {
      if (j < NIN) x_h[j] = (_Float16)x[(size_t)(t * BATCH + b) * NIN + j];
    }
    __syncthreads();

    float partial = 0.f;
    if (q == 0) {
      float S   = red_s[0] + red_s[1] + red_s[2] + red_s[3];
      float sxn = sx + A_STD * (1.f - sx) - DT_S * su * sx * h;
      float v   = U_PAR * (1.f - su) * S;
      float sun = su + A_STF * (U_PAR - su) + DT_S * v;
      sxn = fminf(fmaxf(sxn, 0.f), 1.f);
      sun = fminf(fmaxf(sun, 0.f), 1.f);
      float g = h * sxn * sun;
      g_h[j] = (_Float16)g;
      sx = sxn; su = sun;
      size_t row = (size_t)((t + 1) * BATCH + b) * NH + j;
      out[SX_OFF + row * NH] = sxn;
      out[SU_OFF + row * NH] = sun;
    } else {
      float xw = 0.f;
      const half2_t* x2 = (const half2_t*)x_h;
#pragma unroll
      for (int k = 0; k < 32; ++k) xw = fdot2f(win2[k], x2[k], xw);
      xw_s[j] = xw;
    }
    __syncthreads();

    {
      const half2_t* g2 = (const half2_t*)g_h;
#pragma unroll
      for (int k = 0; k < 64; ++k) partial = fdot2f(w2[k], g2[q * 64 + k], partial);
    }
    if (q == 1) p_s[j] = partial;
    __syncthreads();

    if (q == 0) {
      float rec = partial + p_s[j];
      float hn  = 0.9f * h + 0.1f * (rec + bias) + xw_s[j];
      hn = fmaxf(hn, 0.f);
      out[H_OFF + ((size_t)(t + 1) * BATCH + b) * NH + j] = hn;
      h = hn;
    }
  }
}

__global__ __launch_bounds__(256) void rnn_yhead(
    const float* __restrict__ Wout, const float* __restrict__ Woutb,
    float* __restrict__ out)
{
  const int tb = blockIdx.x;
  const int t  = tb / BATCH, b = tb % BATCH;
  const int j  = threadIdx.x;
  __shared__ float red[NOUT][5];

  float h = out[H_OFF + ((size_t)(t + 1) * BATCH + b) * NH + j];
  const float* wrow = Wout + j * NOUT;
#pragma unroll
  for (int o = 0; o < NOUT; ++o) {
    float v = h * wrow[o];
#pragma unroll
    for (int m = 1; m < 64; m <<= 1) v += __shfl_xor(v, m, 64);
    if ((j & 63) == 0) red[o][j >> 6] = v;
  }
  __syncthreads();
  if (j < NOUT) {
    float v = red[j][0] + red[j][1] + red[j][2] + red[j][3] + Woutb[j];
    out[Y_OFF + (size_t)tb * NOUT + j] = 1.f / (1.f + expf(-v));
  }
}

__global__ __launch_bounds__(256) void rnn_bcast(float* __restrict__ out)
{
  const size_t base = SX_OFF;
  const int ROWS = 32;
  __shared__ float sval[ROWS];
  const int ngroups = (2 * PLANE) / ROWS;
  for (int grp = blockIdx.x; grp < ngroups; grp += gridDim.x) {
    size_t r0 = (size_t)grp * ROWS;
    if (threadIdx.x < ROWS) sval[threadIdx.x] = out[base + (r0 + threadIdx.x) * NH];
    __syncthreads();
#pragma unroll
    for (int p = 0; p < 8; ++p) {
      int id = p * 256 + threadIdx.x;
      int r = id >> 6, c = id & 63;
      float v = sval[r];
      float4_t f4 = {v, v, v, v};
      float4_t* dst = (float4_t*)(out + base + (r0 + r) * NH);
      __builtin_nontemporal_store(f4, dst + c);
    }
    __syncthreads();
  }
}

extern "C" void kernel_launch(void* const* d_in, const int* in_sizes, int n_in,
                              void* d_out, int out_size, void* d_ws, size_t ws_size,
                              hipStream_t stream) {
  (void)in_sizes; (void)n_in; (void)out_size;
  const float* x     = (const float*)d_in[0];
  const float* Win   = (const float*)d_in[1];
  const float* Wrec  = (const float*)d_in[2];
  const float* Wbias = (const float*)d_in[3];
  const float* Wout  = (const float*)d_in[4];
  const float* Woutb = (const float*)d_in[5];
  float* out = (float*)d_out;

  // ws layout: wsx64 (PLANE u64) | wsu64 (PLANE u64)
  const size_t WS_NEED = 2 * (size_t)PLANE * sizeof(u64);
  u64* wsx64 = (u64*)d_ws;
  u64* wsu64 = wsx64 + PLANE;

  bool coop_ok = (ws_size >= WS_NEED);
  int dev = 0, cus = 0, occ = 0;
  if (coop_ok && hipGetDevice(&dev) != hipSuccess) coop_ok = false;
  if (coop_ok && hipDeviceGetAttribute(&cus, hipDeviceAttributeMultiprocessorCount,
                                       dev) != hipSuccess) coop_ok = false;
  if (coop_ok && hipOccupancyMaxActiveBlocksPerMultiprocessor(
                     &occ, (const void*)rnn_fused, 256, 0) != hipSuccess) coop_ok = false;
  int grid = occ * cus;
  if (grid > BATCH + 4096) grid = BATCH + 4096;
  if (grid < 80) coop_ok = false;

  if (coop_ok) {
    void* args[] = {(void*)&x, (void*)&Win, (void*)&Wrec, (void*)&Wbias,
                    (void*)&Wout, (void*)&Woutb, (void*)&out,
                    (void*)&wsx64, (void*)&wsu64};
    hipError_t e = hipLaunchCooperativeKernel((const void*)rnn_fused, dim3(grid),
                                              dim3(256), args, 0, stream);
    if (e == hipSuccess) return;
  }

  // fallback: proven serialized path
  hipLaunchKernelGGL(rnn_phase1, dim3(BATCH), dim3(512), 0, stream,
                     x, Win, Wrec, Wbias, out);
  hipLaunchKernelGGL(rnn_yhead, dim3(T_STEPS * BATCH), dim3(256), 0, stream,
                     Wout, Woutb, out);
  hipLaunchKernelGGL(rnn_bcast, dim3(2048), dim3(256), 0, stream, out);
}

// Round 12
// 177.125 us; speedup vs baseline: 1.1008x; 1.1008x over previous
//
#include <hip/hip_runtime.h>

typedef _Float16 half2_t __attribute__((ext_vector_type(2)));
typedef float float4_t __attribute__((ext_vector_type(4)));
typedef unsigned long long u64;

#define U_PAR 0.45f
#define A_STD 0.006667f
#define A_STF 0.05f
#define DT_S  0.01f

#define T_STEPS 64
#define BATCH   16
#define NIN     64
#define NH      256
#define NOUT    16

// d_out layout (floats): h_all (65,16,256) | y (64,16,16) | sx_all (65,16,256,256) | su_all
#define H_OFF  0
#define H_SZ   ((T_STEPS + 1) * BATCH * NH)            // 266240
#define Y_OFF  H_SZ
#define Y_SZ   (T_STEPS * BATCH * NOUT)                // 16384
#define SX_OFF (Y_OFF + Y_SZ)                          // 282624
#define PLANE  ((T_STEPS + 1) * BATCH * NH)            // 266240 compact elems per array
#define SX_SZ  ((size_t)PLANE * NH)
#define SU_OFF ((size_t)SX_OFF + SX_SZ)

#define GROUP    32                                     // rows per consumer iteration
#define N_ROWS   (2 * PLANE)                            // 532480 broadcast rows
#define N_GROUPS (N_ROWS / GROUP)                       // 16640
#define TAG_BASE 0x5EED0000u                            // high word of packed u64

static __device__ __forceinline__ float fdot2f(half2_t a, half2_t b, float c) {
#if __has_builtin(__builtin_amdgcn_fdot2)
  return __builtin_amdgcn_fdot2(a, b, c, false);
#else
  return c + (float)a.x * (float)b.x + (float)a.y * (float)b.y;
#endif
}

// LDS-only barrier: waits ds ops, NOT outstanding global stores (vmcnt).
static __device__ __forceinline__ void bar_lds() {
  asm volatile("s_waitcnt lgkmcnt(0)" ::: "memory");
  __builtin_amdgcn_s_barrier();
  asm volatile("" ::: "memory");
}

// ======================= Fused cooperative kernel ===========================
// Round-12 thesis: round 10's producer restructure was right, but its 90KB
// static LDS silently cut CONSUMER occupancy to 1 block/CU (static __shared__
// is allocated for every block). This version keeps the fast 2-barrier
// producer but with ~34KB LDS so consumers stay at 4 blocks/CU (16 waves/CU
// of NT-store issue — the round-7 configuration that sustains ~4+ TB/s).
// blocks 0..15: producer (batch b): per-step chain = {shfl-reduce -> B1 ->
//   sx/su + tags + xw(dot from prefetched x) -> B2 -> 128-fdot2 -> h}. x is
//   double-buffered in LDS one step ahead; h saved to fp16 history; y-head
//   runs after the loop. Tagged-u64 publication (single-copy atomic) needs
//   no store ordering; barriers are LDS-only.
// blocks 16.. : consumers — byte-identical to round 7 (best, 136.8us).
__global__ __launch_bounds__(256, 2) void rnn_fused(
    const float* __restrict__ x, const float* __restrict__ Win,
    const float* __restrict__ Wrec, const float* __restrict__ Wbias,
    const float* __restrict__ Wout, const float* __restrict__ Woutb,
    float* __restrict__ out, u64* __restrict__ wsx64, u64* __restrict__ wsu64)
{
  if (blockIdx.x < BATCH) {
    // ----------------------------- producer ---------------------------------
    __builtin_amdgcn_s_setprio(1);
    const int b = blockIdx.x;
    const int j = threadIdx.x;           // 0..255
    const int wv = j >> 6, lane = j & 63;

    __shared__ __align__(16) _Float16 g_h[NH];              // 512 B
    __shared__ __align__(16) _Float16 x_h[2][NIN];          // 256 B
    __shared__ __align__(16) _Float16 hs16[T_STEPS][NH];    // 32 KB h-history
    __shared__ float red_s[4];
    __shared__ float ypart[4][NOUT];                        // 256 B

    half2_t w2[128];
#pragma unroll
    for (int k = 0; k < 128; ++k) {
      float a0 = Wrec[(2 * k) * NH + j];
      float a1 = Wrec[(2 * k + 1) * NH + j];
      half2_t v; v.x = (_Float16)a0; v.y = (_Float16)a1;
      w2[k] = v;
    }
    half2_t win2[32];
#pragma unroll
    for (int k = 0; k < 32; ++k) {
      float a0 = Win[(2 * k) * NH + j];
      float a1 = Win[(2 * k + 1) * NH + j];
      half2_t v; v.x = (_Float16)a0; v.y = (_Float16)a1;
      win2[k] = v;
    }
    const int chunk = j >> 4, o = j & 15;
    float wseg[16];
#pragma unroll
    for (int m = 0; m < 16; ++m) wseg[m] = Wout[(chunk * 16 + m) * NOUT + o];
    const float bias = Wbias[j];

    float h = 0.f, sx = 1.f, su = U_PAR;   // su0 = U_std + 1 = 0.45
    out[H_OFF + b * NH + j] = 0.f;         // h_all[0]
    if (j < NIN) x_h[0][j] = (_Float16)x[(size_t)(0 * BATCH + b) * NIN + j];

    for (int t = 0; t < T_STEPS; ++t) {
      const int cur = t & 1;
      // prefetch next step's x (WAR covered: x_h[cur^1] last read before B2
      // of iteration t-1; this write is after that barrier)
      if (j < NIN && t + 1 < T_STEPS)
        x_h[cur ^ 1][j] = (_Float16)x[(size_t)((t + 1) * BATCH + b) * NIN + j];

      float s = h;
#pragma unroll
      for (int m = 1; m < 64; m <<= 1) s += __shfl_xor(s, m, 64);
      if (lane == 0) red_s[wv] = s;
      bar_lds();                                         // B1: red_s, x_h[cur]

      float S = red_s[0] + red_s[1] + red_s[2] + red_s[3];
      float sxn = sx + A_STD * (1.f - sx) - DT_S * su * sx * h;
      float sun = su + A_STF * (U_PAR - su) + DT_S * (U_PAR * (1.f - su) * S);
      sxn = fminf(fmaxf(sxn, 0.f), 1.f);
      sun = fminf(fmaxf(sun, 0.f), 1.f);
      g_h[j] = (_Float16)(h * sxn * sun);
      const int row = (t + 1) * BATCH + b;               // compact state row
      {
        u64 tg = (u64)(TAG_BASE | (unsigned)row) << 32;
        __hip_atomic_store(&wsx64[(size_t)row * NH + j],
                           tg | (u64)__float_as_uint(sxn),
                           __ATOMIC_RELAXED, __HIP_MEMORY_SCOPE_AGENT);
        __hip_atomic_store(&wsu64[(size_t)row * NH + j],
                           tg | (u64)__float_as_uint(sun),
                           __ATOMIC_RELAXED, __HIP_MEMORY_SCOPE_AGENT);
      }
      sx = sxn; su = sun;

      float xw = 0.f;
      {
        const half2_t* x2 = (const half2_t*)x_h[cur];
        float xa0 = 0.f, xa1 = 0.f;
#pragma unroll
        for (int k = 0; k < 32; k += 2) {
          xa0 = fdot2f(win2[k], x2[k], xa0);
          xa1 = fdot2f(win2[k + 1], x2[k + 1], xa1);
        }
        xw = xa0 + xa1;
      }
      bar_lds();                                         // B2: g_h ready

      float a0 = 0.f, a1 = 0.f, a2 = 0.f, a3 = 0.f;
      {
        const half2_t* g2 = (const half2_t*)g_h;
#pragma unroll
        for (int k = 0; k < 128; k += 4) {
          a0 = fdot2f(w2[k],     g2[k],     a0);
          a1 = fdot2f(w2[k + 1], g2[k + 1], a1);
          a2 = fdot2f(w2[k + 2], g2[k + 2], a2);
          a3 = fdot2f(w2[k + 3], g2[k + 3], a3);
        }
      }
      float rec = (a0 + a1) + (a2 + a3);
      float hn = fmaxf(0.9f * h + 0.1f * (rec + bias) + xw, 0.f);
      out[H_OFF + (size_t)row * NH + j] = hn;
      hs16[t][j] = (_Float16)hn;
      h = hn;
    }

    // ---------------- y-head (off the critical chain) -----------------------
    bar_lds();                           // hs16 complete
    for (int t = 0; t < T_STEPS; ++t) {
      float yp = 0.f;
      {
        float y0 = 0.f, y1 = 0.f;
#pragma unroll
        for (int m = 0; m < 16; m += 2) {
          y0 = fmaf((float)hs16[t][chunk * 16 + m],     wseg[m],     y0);
          y1 = fmaf((float)hs16[t][chunk * 16 + m + 1], wseg[m + 1], y1);
        }
        yp = y0 + y1;
      }
      yp += __shfl_xor(yp, 16, 64);
      yp += __shfl_xor(yp, 32, 64);
      if (lane < NOUT) ypart[wv][lane] = yp;
      bar_lds();                         // ypart ready
      if (j < NOUT) {
        float v = ypart[0][j] + ypart[1][j] + ypart[2][j] + ypart[3][j] + Woutb[j];
        out[Y_OFF + (size_t)(t * BATCH + b) * NOUT + j] = 1.f / (1.f + expf(-v));
      }
      bar_lds();                         // WAR on ypart
    }
    __builtin_amdgcn_s_setprio(0);
  } else {
    // --------------- consumers (byte-identical to round 7) ------------------
    const int nCons = (int)gridDim.x - BATCH;
    const int cb    = (int)blockIdx.x - BATCH;
    const int tid   = threadIdx.x;
    __shared__ float sval[2][GROUP];

    auto stageFn = [&](int g, int buf) {
      int r0    = g * GROUP;
      int t     = r0 >> 13;          // 8192 rows per t-slice
      int rem   = r0 & 8191;
      int which = rem >> 12;
      int b     = (rem >> 8) & 15;
      int i0    = rem & 255;
      if (t == 0) {
        sval[buf][tid] = which ? U_PAR : 1.0f;
        return;
      }
      int row = (t << 4) | b;
      unsigned exp = TAG_BASE | (unsigned)row;
      const u64* src = (which ? wsu64 : wsx64) + (size_t)row * NH + i0 + tid;
      u64 v = __hip_atomic_load(src, __ATOMIC_RELAXED, __HIP_MEMORY_SCOPE_AGENT);
      while ((unsigned)(v >> 32) != exp) {
        __builtin_amdgcn_s_sleep(32);
        v = __hip_atomic_load(src, __ATOMIC_RELAXED, __HIP_MEMORY_SCOPE_AGENT);
      }
      sval[buf][tid] = __uint_as_float((unsigned)(v & 0xFFFFFFFFu));
    };

    if (cb < N_GROUPS && tid < GROUP) stageFn(cb, 0);
    int k = 0;
    for (int g = cb; g < N_GROUPS; g += nCons, ++k) {
      int buf = k & 1;
      bar_lds();                     // sval[buf] ready; WAR from iter k-1 done
      int gn = g + nCons;
      if (gn < N_GROUPS && tid < GROUP) stageFn(gn, buf ^ 1);

      int r0    = g * GROUP;
      int t     = r0 >> 13;
      int rem   = r0 & 8191;
      int which = rem >> 12;
      int b     = (rem >> 8) & 15;
      int i0    = rem & 255;
      size_t rowbase = (size_t)(((t << 4) | b) * NH + i0);
      float* dstBase = out + (which ? SU_OFF : (size_t)SX_OFF) + rowbase * NH;
#pragma unroll
      for (int p = 0; p < 8; ++p) {  // 32 rows * 64 float4 = 32 KB
        int id = p * 256 + tid;
        int rr = id >> 6, c = id & 63;
        float v = sval[buf][rr];
        float4_t f4 = {v, v, v, v};
        __builtin_nontemporal_store(f4, (float4_t*)(dstBase + (size_t)rr * NH) + c);
      }
    }
  }
}

// ===================== Fallback: proven 3-kernel path =======================
__global__ __launch_bounds__(512) void rnn_phase1(
    const float* __restrict__ x, const float* __restrict__ Win,
    const float* __restrict__ Wrec, const float* __restrict__ Wbias,
    float* __restrict__ out)
{
  const int b   = blockIdx.x;
  const int tid = threadIdx.x;
  const int j   = tid & 255;
  const int q   = tid >> 8;

  __shared__ __align__(16) _Float16 g_h[NH];
  __shared__ __align__(16) _Float16 x_h[NIN];
  __shared__ float p_s[NH];
  __shared__ float xw_s[NH];
  __shared__ float red_s[8];

  half2_t w2[64];
#pragma unroll
  for (int k = 0; k < 64; ++k) {
    float a0 = Wrec[(q * 128 + 2 * k) * NH + j];
    float a1 = Wrec[(q * 128 + 2 * k + 1) * NH + j];
    half2_t v; v.x = (_Float16)a0; v.y = (_Float16)a1;
    w2[k] = v;
  }
  half2_t win2[32];
  if (q == 1) {
#pragma unroll
    for (int k = 0; k < 32; ++k) {
      float a0 = Win[(2 * k) * NH + j];
      float a1 = Win[(2 * k + 1) * NH + j];
      half2_t v; v.x = (_Float16)a0; v.y = (_Float16)a1;
      win2[k] = v;
    }
  }

  float h = 0.f, sx = 1.f, su = U_PAR;
  float bias = 0.f;
  if (q == 0) bias = Wbias[j];

  if (q == 0) {
    out[H_OFF + b * NH + j] = 0.f;
    size_t row0 = (size_t)b * NH + j;
    out[SX_OFF + row0 * NH] = 1.f;
    out[SU_OFF + row0 * NH] = U_PAR;
  }

  for (int t = 0; t < T_STEPS; ++t) {
    if (q == 0) {
      float s = h;
#pragma unroll
      for (int m = 1; m < 64; m <<= 1) s += __shfl_xor(s, m, 64);
      if ((tid & 63) == 0) red_s[tid >> 6] = s;
    } else {
      if (j < NIN) x_h[j] = (_Float16)x[(size_t)(t * BATCH + b) * NIN + j];
    }
    __syncthreads();

    float partial = 0.f;
    if (q == 0) {
      float S   = red_s[0] + red_s[1] + red_s[2] + red_s[3];
      float sxn = sx + A_STD * (1.f - sx) - DT_S * su * sx * h;
      float v   = U_PAR * (1.f - su) * S;
      float sun = su + A_STF * (U_PAR - su) + DT_S * v;
      sxn = fminf(fmaxf(sxn, 0.f), 1.f);
      sun = fminf(fmaxf(sun, 0.f), 1.f);
      float g = h * sxn * sun;
      g_h[j] = (_Float16)g;
      sx = sxn; su = sun;
      size_t row = (size_t)((t + 1) * BATCH + b) * NH + j;
      out[SX_OFF + row * NH] = sxn;
      out[SU_OFF + row * NH] = sun;
    } else {
      float xw = 0.f;
      const half2_t* x2 = (const half2_t*)x_h;
#pragma unroll
      for (int k = 0; k < 32; ++k) xw = fdot2f(win2[k], x2[k], xw);
      xw_s[j] = xw;
    }
    __syncthreads();

    {
      const half2_t* g2 = (const half2_t*)g_h;
#pragma unroll
      for (int k = 0; k < 64; ++k) partial = fdot2f(w2[k], g2[q * 64 + k], partial);
    }
    if (q == 1) p_s[j] = partial;
    __syncthreads();

    if (q == 0) {
      float rec = partial + p_s[j];
      float hn  = 0.9f * h + 0.1f * (rec + bias) + xw_s[j];
      hn = fmaxf(hn, 0.f);
      out[H_OFF + ((size_t)(t + 1) * BATCH + b) * NH + j] = hn;
      h = hn;
    }
  }
}

__global__ __launch_bounds__(256) void rnn_yhead(
    const float* __restrict__ Wout, const float* __restrict__ Woutb,
    float* __restrict__ out)
{
  const int tb = blockIdx.x;
  const int t  = tb / BATCH, b = tb % BATCH;
  const int j  = threadIdx.x;
  __shared__ float red[NOUT][5];

  float h = out[H_OFF + ((size_t)(t + 1) * BATCH + b) * NH + j];
  const float* wrow = Wout + j * NOUT;
#pragma unroll
  for (int o = 0; o < NOUT; ++o) {
    float v = h * wrow[o];
#pragma unroll
    for (int m = 1; m < 64; m <<= 1) v += __shfl_xor(v, m, 64);
    if ((j & 63) == 0) red[o][j >> 6] = v;
  }
  __syncthreads();
  if (j < NOUT) {
    float v = red[j][0] + red[j][1] + red[j][2] + red[j][3] + Woutb[j];
    out[Y_OFF + (size_t)tb * NOUT + j] = 1.f / (1.f + expf(-v));
  }
}

__global__ __launch_bounds__(256) void rnn_bcast(float* __restrict__ out)
{
  const size_t base = SX_OFF;
  const int ROWS = 32;
  __shared__ float sval[ROWS];
  const int ngroups = (2 * PLANE) / ROWS;
  for (int grp = blockIdx.x; grp < ngroups; grp += gridDim.x) {
    size_t r0 = (size_t)grp * ROWS;
    if (threadIdx.x < ROWS) sval[threadIdx.x] = out[base + (r0 + threadIdx.x) * NH];
    __syncthreads();
#pragma unroll
    for (int p = 0; p < 8; ++p) {
      int id = p * 256 + threadIdx.x;
      int r = id >> 6, c = id & 63;
      float v = sval[r];
      float4_t f4 = {v, v, v, v};
      float4_t* dst = (float4_t*)(out + base + (r0 + r) * NH);
      __builtin_nontemporal_store(f4, dst + c);
    }
    __syncthreads();
  }
}

extern "C" void kernel_launch(void* const* d_in, const int* in_sizes, int n_in,
                              void* d_out, int out_size, void* d_ws, size_t ws_size,
                              hipStream_t stream) {
  (void)in_sizes; (void)n_in; (void)out_size;
  const float* x     = (const float*)d_in[0];
  const float* Win   = (const float*)d_in[1];
  const float* Wrec  = (const float*)d_in[2];
  const float* Wbias = (const float*)d_in[3];
  const float* Wout  = (const float*)d_in[4];
  const float* Woutb = (const float*)d_in[5];
  float* out = (float*)d_out;

  // ws layout: wsx64 (PLANE u64) | wsu64 (PLANE u64)
  const size_t WS_NEED = 2 * (size_t)PLANE * sizeof(u64);
  u64* wsx64 = (u64*)d_ws;
  u64* wsu64 = wsx64 + PLANE;

  bool coop_ok = (ws_size >= WS_NEED);
  int dev = 0, cus = 0, occ = 0;
  if (coop_ok && hipGetDevice(&dev) != hipSuccess) coop_ok = false;
  if (coop_ok && hipDeviceGetAttribute(&cus, hipDeviceAttributeMultiprocessorCount,
                                       dev) != hipSuccess) coop_ok = false;
  if (coop_ok && hipOccupancyMaxActiveBlocksPerMultiprocessor(
                     &occ, (const void*)rnn_fused, 256, 0) != hipSuccess) coop_ok = false;
  int grid = occ * cus;
  if (grid > BATCH + 4096) grid = BATCH + 4096;
  if (grid < 80) coop_ok = false;

  if (coop_ok) {
    void* args[] = {(void*)&x, (void*)&Win, (void*)&Wrec, (void*)&Wbias,
                    (void*)&Wout, (void*)&Woutb, (void*)&out,
                    (void*)&wsx64, (void*)&wsu64};
    hipError_t e = hipLaunchCooperativeKernel((const void*)rnn_fused, dim3(grid),
                                              dim3(256), args, 0, stream);
    if (e == hipSuccess) return;
  }

  // fallback: proven serialized path
  hipLaunchKernelGGL(rnn_phase1, dim3(BATCH), dim3(512), 0, stream,
                     x, Win, Wrec, Wbias, out);
  hipLaunchKernelGGL(rnn_yhead, dim3(T_STEPS * BATCH), dim3(256), 0, stream,
                     Wout, Woutb, out);
  hipLaunchKernelGGL(rnn_bcast, dim3(2048), dim3(256), 0, stream, out);
}

// Round 13
// 123.400 us; speedup vs baseline: 1.5801x; 1.4354x over previous
//
#include <hip/hip_runtime.h>

typedef _Float16 half2_t __attribute__((ext_vector_type(2)));
typedef float float4_t __attribute__((ext_vector_type(4)));
typedef unsigned long long u64;

#define U_PAR 0.45f
#define A_STD 0.006667f
#define A_STF 0.05f
#define DT_S  0.01f

#define T_STEPS 64
#define BATCH   16
#define NIN     64
#define NH      256
#define NOUT    16

// d_out layout (floats): h_all (65,16,256) | y (64,16,16) | sx_all (65,16,256,256) | su_all
#define H_OFF  0
#define H_SZ   ((T_STEPS + 1) * BATCH * NH)            // 266240
#define Y_OFF  H_SZ
#define Y_SZ   (T_STEPS * BATCH * NOUT)                // 16384
#define SX_OFF (Y_OFF + Y_SZ)                          // 282624
#define PLANE  ((T_STEPS + 1) * BATCH * NH)            // 266240 compact elems per array
#define SX_SZ  ((size_t)PLANE * NH)
#define SU_OFF ((size_t)SX_OFF + SX_SZ)

#define GROUP    32                                     // rows per consumer iteration
#define N_ROWS   (2 * PLANE)                            // 532480 broadcast rows
#define N_GROUPS (N_ROWS / GROUP)                       // 16640
#define TAG_BASE 0x5EED0000u                            // high word of packed u64

static __device__ __forceinline__ float fdot2f(half2_t a, half2_t b, float c) {
#if __has_builtin(__builtin_amdgcn_fdot2)
  return __builtin_amdgcn_fdot2(a, b, c, false);
#else
  return c + (float)a.x * (float)b.x + (float)a.y * (float)b.y;
#endif
}

// LDS-only barrier: waits ds ops, NOT outstanding global stores (vmcnt).
static __device__ __forceinline__ void bar_lds() {
  asm volatile("s_waitcnt lgkmcnt(0)" ::: "memory");
  __builtin_amdgcn_s_barrier();
  asm volatile("" ::: "memory");
}

// ======================= Fused cooperative kernel ===========================
// Round-13 thesis: the kernel's VGPR count couples producer code to CONSUMER
// occupancy (every block allocates the max-branch registers). Earlier
// producers declared 176+ regs of arrays -> spill/remat (W_rec re-streamed
// from L2 every step = the 2us step) or, when regalloc kept them, >128 VGPR
// halved consumer waves (the 177-179us regressions). Fix: 512-thread blocks,
// k-range split (q = tid>>8) so each thread holds only w2[64];
// __launch_bounds__(512,4) FORCES <=128 VGPR -> consumers pinned at 16
// waves/CU. Producer also off-loads everything from the serial chain:
// x staged to LDS, xw precomputed (slots reused as fp16 h-history), y-head
// after the loop; 3 LDS-only barriers/step; tagged-u64 publication
// (single-copy atomic, no ordering needed).
// Consumers: round-7 protocol (GROUP=32, NT stores, double-buffered),
// adapted to 512 threads (4 float4 stores/thread).
__global__ __launch_bounds__(512, 4) void rnn_fused(
    const float* __restrict__ x, const float* __restrict__ Win,
    const float* __restrict__ Wrec, const float* __restrict__ Wbias,
    const float* __restrict__ Wout, const float* __restrict__ Woutb,
    float* __restrict__ out, u64* __restrict__ wsx64, u64* __restrict__ wsu64)
{
  // static LDS (allocated per block, all branches): ~42.5 KB
  __shared__ __align__(16) _Float16 g_h[NH];               // 512 B
  __shared__ __align__(16) _Float16 x16[T_STEPS][NIN];     // 8 KB
  __shared__ __align__(16) _Float16 xw16[T_STEPS][NH];     // 32 KB (xw -> h-history)
  __shared__ float p_s[NH];                                // 1 KB
  __shared__ float red_s[4];
  __shared__ float sval[2][GROUP];                         // consumer staging

  if (blockIdx.x < BATCH) {
    // ----------------------------- producer ---------------------------------
    __builtin_amdgcn_s_setprio(1);
    const int b    = blockIdx.x;
    const int tid  = threadIdx.x;        // 0..511
    const int j    = tid & 255;
    const int q    = tid >> 8;           // k-half: 0 or 1
    const int wv   = tid >> 6;           // 0..7
    const int lane = tid & 63;

    // stage x[.,b,:] -> LDS fp16 (one-time, coalesced-ish)
#pragma unroll
    for (int e = 0; e < 8; ++e) {
      int idx = e * 512 + tid;           // 0..4095
      int t = idx >> 6, i = idx & 63;
      x16[t][i] = (_Float16)x[(size_t)(t * BATCH + b) * NIN + i];
    }
    bar_lds();                           // x16 ready

    // precompute xw[t][j] for t in q's half (win2 regs die after this)
    {
      half2_t win2[32];
#pragma unroll
      for (int k = 0; k < 32; ++k) {
        float a0 = Win[(2 * k) * NH + j];
        float a1 = Win[(2 * k + 1) * NH + j];
        half2_t v; v.x = (_Float16)a0; v.y = (_Float16)a1;
        win2[k] = v;
      }
      for (int tt = 0; tt < 32; ++tt) {
        int t = q * 32 + tt;
        const half2_t* x2 = (const half2_t*)x16[t];
        float xa0 = 0.f, xa1 = 0.f;
#pragma unroll
        for (int k = 0; k < 32; k += 2) {
          xa0 = fdot2f(win2[k], x2[k], xa0);
          xa1 = fdot2f(win2[k + 1], x2[k + 1], xa1);
        }
        xw16[t][j] = (_Float16)(xa0 + xa1);
      }
    }

    // W_rec fragment: rows [q*128, q*128+128) of column j -> 64 half2 regs
    half2_t w2[64];
#pragma unroll
    for (int k = 0; k < 64; ++k) {
      float a0 = Wrec[(q * 128 + 2 * k) * NH + j];
      float a1 = Wrec[(q * 128 + 2 * k + 1) * NH + j];
      half2_t v; v.x = (_Float16)a0; v.y = (_Float16)a1;
      w2[k] = v;
    }
    const float bias = (q == 0) ? Wbias[j] : 0.f;

    float h = 0.f, sx = 1.f, su = U_PAR;   // su0 = U_std + 1 = 0.45
    if (q == 0) out[H_OFF + b * NH + j] = 0.f;   // h_all[0]
    bar_lds();                           // xw16 fully written (cross-q reads)

    for (int t = 0; t < T_STEPS; ++t) {
      if (q == 0) {
        float s = h;
#pragma unroll
        for (int m = 1; m < 64; m <<= 1) s += __shfl_xor(s, m, 64);
        if (lane == 0) red_s[wv] = s;    // wv 0..3
      }
      bar_lds();                                         // B1: red_s ready

      float xwv = 0.f;
      if (q == 0) {
        float S = red_s[0] + red_s[1] + red_s[2] + red_s[3];
        float sxn = sx + A_STD * (1.f - sx) - DT_S * su * sx * h;
        float sun = su + A_STF * (U_PAR - su) + DT_S * (U_PAR * (1.f - su) * S);
        sxn = fminf(fmaxf(sxn, 0.f), 1.f);
        sun = fminf(fmaxf(sun, 0.f), 1.f);
        g_h[j] = (_Float16)(h * sxn * sun);
        const int row = (t + 1) * BATCH + b;             // compact state row
        u64 tg = (u64)(TAG_BASE | (unsigned)row) << 32;
        __hip_atomic_store(&wsx64[(size_t)row * NH + j],
                           tg | (u64)__float_as_uint(sxn),
                           __ATOMIC_RELAXED, __HIP_MEMORY_SCOPE_AGENT);
        __hip_atomic_store(&wsu64[(size_t)row * NH + j],
                           tg | (u64)__float_as_uint(sun),
                           __ATOMIC_RELAXED, __HIP_MEMORY_SCOPE_AGENT);
        sx = sxn; su = sun;
        xwv = (float)xw16[t][j];
      }
      bar_lds();                                         // B2: g_h ready

      float a0 = 0.f, a1 = 0.f;
      {
        const half2_t* g2 = (const half2_t*)g_h + q * 64;
#pragma unroll
        for (int k = 0; k < 64; k += 2) {
          a0 = fdot2f(w2[k],     g2[k],     a0);
          a1 = fdot2f(w2[k + 1], g2[k + 1], a1);
        }
      }
      float partial = a0 + a1;
      if (q == 1) p_s[j] = partial;
      bar_lds();                                         // B3: p_s ready

      if (q == 0) {
        float rec = partial + p_s[j];
        float hn = fmaxf(0.9f * h + 0.1f * (rec + bias) + xwv, 0.f);
        out[H_OFF + (size_t)((t + 1) * BATCH + b) * NH + j] = hn;
        xw16[t][j] = (_Float16)hn;       // own slot -> h-history (no race)
        h = hn;
      }
    }

    // ---------------- y-head (off the critical chain) -----------------------
    bar_lds();                           // h-history complete
    {
      const int part = lane >> 4;        // 0..3 (64-j chunk)
      const int o    = lane & 15;
      for (int tt = 0; tt < 8; ++tt) {
        int t = wv * 8 + tt;             // each of 8 waves owns 8 t's
        float acc = 0.f;
#pragma unroll 8
        for (int j2 = 0; j2 < 64; ++j2) {
          int jj = part * 64 + j2;
          acc = fmaf((float)xw16[t][jj], Wout[jj * NOUT + o], acc);
        }
        acc += __shfl_xor(acc, 16, 64);
        acc += __shfl_xor(acc, 32, 64);
        if (lane < NOUT) {
          out[Y_OFF + (size_t)(t * BATCH + b) * NOUT + lane] =
              1.f / (1.f + expf(-(acc + Woutb[lane])));
        }
      }
    }
    __builtin_amdgcn_s_setprio(0);
  } else {
    // --------------------- consumers (round-7 protocol) ---------------------
    const int nCons = (int)gridDim.x - BATCH;
    const int cb    = (int)blockIdx.x - BATCH;
    const int tid   = threadIdx.x;       // 0..511

    auto stageFn = [&](int g, int buf) {
      int r0    = g * GROUP;
      int t     = r0 >> 13;          // 8192 rows per t-slice
      int rem   = r0 & 8191;
      int which = rem >> 12;
      int b     = (rem >> 8) & 15;
      int i0    = rem & 255;
      if (t == 0) {
        sval[buf][tid] = which ? U_PAR : 1.0f;
        return;
      }
      int row = (t << 4) | b;
      unsigned exp = TAG_BASE | (unsigned)row;
      const u64* src = (which ? wsu64 : wsx64) + (size_t)row * NH + i0 + tid;
      u64 v = __hip_atomic_load(src, __ATOMIC_RELAXED, __HIP_MEMORY_SCOPE_AGENT);
      while ((unsigned)(v >> 32) != exp) {
        __builtin_amdgcn_s_sleep(32);
        v = __hip_atomic_load(src, __ATOMIC_RELAXED, __HIP_MEMORY_SCOPE_AGENT);
      }
      sval[buf][tid] = __uint_as_float((unsigned)(v & 0xFFFFFFFFu));
    };

    if (cb < N_GROUPS && tid < GROUP) stageFn(cb, 0);
    int k = 0;
    for (int g = cb; g < N_GROUPS; g += nCons, ++k) {
      int buf = k & 1;
      bar_lds();                     // sval[buf] ready; WAR from iter k-1 done
      int gn = g + nCons;
      if (gn < N_GROUPS && tid < GROUP) stageFn(gn, buf ^ 1);

      int r0    = g * GROUP;
      int t     = r0 >> 13;
      int rem   = r0 & 8191;
      int which = rem >> 12;
      int b     = (rem >> 8) & 15;
      int i0    = rem & 255;
      size_t rowbase = (size_t)(((t << 4) | b) * NH + i0);
      float* dstBase = out + (which ? SU_OFF : (size_t)SX_OFF) + rowbase * NH;
#pragma unroll
      for (int p = 0; p < 4; ++p) {  // 32 rows * 64 float4 = 2048 f4 / 512 thr
        int id = p * 512 + tid;
        int rr = id >> 6, c = id & 63;
        float v = sval[buf][rr];
        float4_t f4 = {v, v, v, v};
        __builtin_nontemporal_store(f4, (float4_t*)(dstBase + (size_t)rr * NH) + c);
      }
    }
  }
}

// ===================== Fallback: proven 3-kernel path =======================
__global__ __launch_bounds__(512) void rnn_phase1(
    const float* __restrict__ x, const float* __restrict__ Win,
    const float* __restrict__ Wrec, const float* __restrict__ Wbias,
    float* __restrict__ out)
{
  const int b   = blockIdx.x;
  const int tid = threadIdx.x;
  const int j   = tid & 255;
  const int q   = tid >> 8;

  __shared__ __align__(16) _Float16 g_h[NH];
  __shared__ __align__(16) _Float16 x_h[NIN];
  __shared__ float p_s[NH];
  __shared__ float xw_s[NH];
  __shared__ float red_s[8];

  half2_t w2[64];
#pragma unroll
  for (int k = 0; k < 64; ++k) {
    float a0 = Wrec[(q * 128 + 2 * k) * NH + j];
    float a1 = Wrec[(q * 128 + 2 * k + 1) * NH + j];
    half2_t v; v.x = (_Float16)a0; v.y = (_Float16)a1;
    w2[k] = v;
  }
  half2_t win2[32];
  if (q == 1) {
#pragma unroll
    for (int k = 0; k < 32; ++k) {
      float a0 = Win[(2 * k) * NH + j];
      float a1 = Win[(2 * k + 1) * NH + j];
      half2_t v; v.x = (_Float16)a0; v.y = (_Float16)a1;
      win2[k] = v;
    }
  }

  float h = 0.f, sx = 1.f, su = U_PAR;
  float bias = 0.f;
  if (q == 0) bias = Wbias[j];

  if (q == 0) {
    out[H_OFF + b * NH + j] = 0.f;
    size_t row0 = (size_t)b * NH + j;
    out[SX_OFF + row0 * NH] = 1.f;
    out[SU_OFF + row0 * NH] = U_PAR;
  }

  for (int t = 0; t < T_STEPS; ++t) {
    if (q == 0) {
      float s = h;
#pragma unroll
      for (int m = 1; m < 64; m <<= 1) s += __shfl_xor(s, m, 64);
      if ((tid & 63) == 0) red_s[tid >> 6] = s;
    } else {
      if (j < NIN) x_h[j] = (_Float16)x[(size_t)(t * BATCH + b) * NIN + j];
    }
    __syncthreads();

    float partial = 0.f;
    if (q == 0) {
      float S   = red_s[0] + red_s[1] + red_s[2] + red_s[3];
      float sxn = sx + A_STD * (1.f - sx) - DT_S * su * sx * h;
      float v   = U_PAR * (1.f - su) * S;
      float sun = su + A_STF * (U_PAR - su) + DT_S * v;
      sxn = fminf(fmaxf(sxn, 0.f), 1.f);
      sun = fminf(fmaxf(sun, 0.f), 1.f);
      float g = h * sxn * sun;
      g_h[j] = (_Float16)g;
      sx = sxn; su = sun;
      size_t row = (size_t)((t + 1) * BATCH + b) * NH + j;
      out[SX_OFF + row * NH] = sxn;
      out[SU_OFF + row * NH] = sun;
    } else {
      float xw = 0.f;
      const half2_t* x2 = (const half2_t*)x_h;
#pragma unroll
      for (int k = 0; k < 32; ++k) xw = fdot2f(win2[k], x2[k], xw);
      xw_s[j] = xw;
    }
    __syncthreads();

    {
      const half2_t* g2 = (const half2_t*)g_h;
#pragma unroll
      for (int k = 0; k < 64; ++k) partial = fdot2f(w2[k], g2[q * 64 + k], partial);
    }
    if (q == 1) p_s[j] = partial;
    __syncthreads();

    if (q == 0) {
      float rec = partial + p_s[j];
      float hn  = 0.9f * h + 0.1f * (rec + bias) + xw_s[j];
      hn = fmaxf(hn, 0.f);
      out[H_OFF + ((size_t)(t + 1) * BATCH + b) * NH + j] = hn;
      h = hn;
    }
  }
}

__global__ __launch_bounds__(256) void rnn_yhead(
    const float* __restrict__ Wout, const float* __restrict__ Woutb,
    float* __restrict__ out)
{
  const int tb = blockIdx.x;
  const int t  = tb / BATCH, b = tb % BATCH;
  const int j  = threadIdx.x;
  __shared__ float red[NOUT][5];

  float h = out[H_OFF + ((size_t)(t + 1) * BATCH + b) * NH + j];
  const float* wrow = Wout + j * NOUT;
#pragma unroll
  for (int o = 0; o < NOUT; ++o) {
    float v = h * wrow[o];
#pragma unroll
    for (int m = 1; m < 64; m <<= 1) v += __shfl_xor(v, m, 64);
    if ((j & 63) == 0) red[o][j >> 6] = v;
  }
  __syncthreads();
  if (j < NOUT) {
    float v = red[j][0] + red[j][1] + red[j][2] + red[j][3] + Woutb[j];
    out[Y_OFF + (size_t)tb * NOUT + j] = 1.f / (1.f + expf(-v));
  }
}

__global__ __launch_bounds__(256) void rnn_bcast(float* __restrict__ out)
{
  const size_t base = SX_OFF;
  const int ROWS = 32;
  __shared__ float sv[ROWS];
  const int ngroups = (2 * PLANE) / ROWS;
  for (int grp = blockIdx.x; grp < ngroups; grp += gridDim.x) {
    size_t r0 = (size_t)grp * ROWS;
    if (threadIdx.x < ROWS) sv[threadIdx.x] = out[base + (r0 + threadIdx.x) * NH];
    __syncthreads();
#pragma unroll
    for (int p = 0; p < 8; ++p) {
      int id = p * 256 + threadIdx.x;
      int r = id >> 6, c = id & 63;
      float v = sv[r];
      float4_t f4 = {v, v, v, v};
      float4_t* dst = (float4_t*)(out + base + (r0 + r) * NH);
      __builtin_nontemporal_store(f4, dst + c);
    }
    __syncthreads();
  }
}

extern "C" void kernel_launch(void* const* d_in, const int* in_sizes, int n_in,
                              void* d_out, int out_size, void* d_ws, size_t ws_size,
                              hipStream_t stream) {
  (void)in_sizes; (void)n_in; (void)out_size;
  const float* x     = (const float*)d_in[0];
  const float* Win   = (const float*)d_in[1];
  const float* Wrec  = (const float*)d_in[2];
  const float* Wbias = (const float*)d_in[3];
  const float* Wout  = (const float*)d_in[4];
  const float* Woutb = (const float*)d_in[5];
  float* out = (float*)d_out;

  // ws layout: wsx64 (PLANE u64) | wsu64 (PLANE u64)
  const size_t WS_NEED = 2 * (size_t)PLANE * sizeof(u64);
  u64* wsx64 = (u64*)d_ws;
  u64* wsu64 = wsx64 + PLANE;

  bool coop_ok = (ws_size >= WS_NEED);
  int dev = 0, cus = 0, occ = 0;
  if (coop_ok && hipGetDevice(&dev) != hipSuccess) coop_ok = false;
  if (coop_ok && hipDeviceGetAttribute(&cus, hipDeviceAttributeMultiprocessorCount,
                                       dev) != hipSuccess) coop_ok = false;
  if (coop_ok && hipOccupancyMaxActiveBlocksPerMultiprocessor(
                     &occ, (const void*)rnn_fused, 512, 0) != hipSuccess) coop_ok = false;
  if (occ < 1) coop_ok = false;
  int grid = occ * cus;
  if (grid > BATCH + 2048) grid = BATCH + 2048;
  if (grid < 80) coop_ok = false;

  if (coop_ok) {
    void* args[] = {(void*)&x, (void*)&Win, (void*)&Wrec, (void*)&Wbias,
                    (void*)&Wout, (void*)&Woutb, (void*)&out,
                    (void*)&wsx64, (void*)&wsu64};
    hipError_t e = hipLaunchCooperativeKernel((const void*)rnn_fused, dim3(grid),
                                              dim3(512), args, 0, stream);
    if (e == hipSuccess) return;
  }

  // fallback: proven serialized path
  hipLaunchKernelGGL(rnn_phase1, dim3(BATCH), dim3(512), 0, stream,
                     x, Win, Wrec, Wbias, out);
  hipLaunchKernelGGL(rnn_yhead, dim3(T_STEPS * BATCH), dim3(256), 0, stream,
                     Wout, Woutb, out);
  hipLaunchKernelGGL(rnn_bcast, dim3(2048), dim3(256), 0, stream, out);
}